// Round 2
// baseline (597.370 us; speedup 1.0000x reference)
//
#include <hip/hip_runtime.h>

static constexpr int Tn = 4096;
static constexpr int Bn = 256;
static constexpr int Hn = 32;

typedef float f4 __attribute__((ext_vector_type(4)));
typedef unsigned int u2v __attribute__((ext_vector_type(2)));

__device__ __forceinline__ float tanh_fast(float s) {
    // tanh(s) = 1 - 2/(exp2(2*log2(e)*s) + 1); correct limits at +-inf
    float e = __builtin_amdgcn_exp2f(s * 2.8853900817779268f);
    float r = __builtin_amdgcn_rcpf(e + 1.0f);
    return __builtin_fmaf(-2.0f, r, 1.0f);
}

template <int CTRL>
__device__ __forceinline__ float ror_f(float v) {
    return __int_as_float(
        __builtin_amdgcn_update_dpp(0, __float_as_int(v), CTRL, 0xF, 0xF, true));
}
template <int CTRL>
__device__ __forceinline__ int ror_i(int v) {
    return __builtin_amdgcn_update_dpp(0, v, CTRL, 0xF, 0xF, true);
}

// gfx950 permlane swaps via builtins: return {new_vdst, new_vsrc} in SSA form.
// Both results are consumed, so the allocator must keep them in distinct
// physical registers -> semantics are deterministic (unlike the inline-asm
// "+v","+v" form, where copy-coalescing of identical inputs could silently
// change the instruction's behavior between the probe and the hot loop).
__device__ __forceinline__ u2v swap16(float a, float b) {
    return __builtin_amdgcn_permlane16_swap(__float_as_uint(a), __float_as_uint(b),
                                            false, false);
}
__device__ __forceinline__ u2v swap32(float a, float b) {
    return __builtin_amdgcn_permlane32_swap(__float_as_uint(a), __float_as_uint(b),
                                            false, false);
}

__global__ __launch_bounds__(64) void rnn_fused_kernel(
    const float* __restrict__ x, const float* __restrict__ h0,
    const float* __restrict__ Wih, const float* __restrict__ Whh,
    const float* __restrict__ bih, const float* __restrict__ bhh,
    const float* __restrict__ Wd, const float* __restrict__ bd,
    float* __restrict__ y_out, float* __restrict__ h_out) {
    const int lid = threadIdx.x;          // 64 threads = 1 wave = 1 batch
    const int b = blockIdx.x;
    const int i_out = lid & 31;           // output (hidden) index this lane owns
    const int k16 = lid & 15;
    const int bblk = lid >> 5;            // j-block (0: j=0..15, 1: j=16..31)
    const int B16 = bblk * 16 + k16;      // h index this lane needs for the dot

    // ---- self-calibration of permlane swap semantics (lane-id probes) ----
    u2v p16 = __builtin_amdgcn_permlane16_swap((unsigned)lid, (unsigned)lid,
                                               false, false);
    const bool selA16 = (p16[0] == (unsigned)(lid ^ 16));
    u2v p32 = __builtin_amdgcn_permlane32_swap((unsigned)lid, (unsigned)lid,
                                               false, false);
    const bool selA32 = (p32[0] == (unsigned)(lid ^ 32));
    const bool rself = (i_out == B16);    // rows 0,3 already hold needed h

    // ---- self-calibrated W permutation for the DPP systolic dot ----
    const float* Wrow = Whh + i_out * Hn + bblk * 16;
    float w0 = Wrow[k16];
#define CALW(R) float w##R = Wrow[ror_i<0x120 + R>(lid) & 15];
    CALW(1) CALW(2) CALW(3) CALW(4) CALW(5) CALW(6) CALW(7) CALW(8)
    CALW(9) CALW(10) CALW(11) CALW(12) CALW(13) CALW(14) CALW(15)
#undef CALW

    const float wih = Wih[i_out];
    const float bias = bih[i_out] + bhh[i_out];
    const float wd = Wd[i_out];
    const float bdv = bd[0];

    float h = h0[b * Hn + i_out];              // lane l holds h_{l&31}

    const float* xb = x + (size_t)b * Tn;      // I == 1
    float* yb = y_out + (size_t)b * Tn;

    f4 xA = *reinterpret_cast<const f4*>(xb);
    f4 xB = *reinterpret_cast<const f4*>(xb + 4);

    auto step = [&](float xv) -> float {
        // redistribute: lanes in rows 1,2 need h from lane (l^16)
        u2v sp = swap16(h, h);
        float sw = __uint_as_float(selA16 ? sp[0] : sp[1]);
        float hb = rself ? h : sw;
        // 16-round DPP systolic partial dot over this lane's j-block
        float a0 = hb * w0;
        float a1 = ror_f<0x121>(hb) * w1;
        float a2 = ror_f<0x122>(hb) * w2;
        float a3 = ror_f<0x123>(hb) * w3;
        a0 = __builtin_fmaf(ror_f<0x124>(hb), w4, a0);
        a1 = __builtin_fmaf(ror_f<0x125>(hb), w5, a1);
        a2 = __builtin_fmaf(ror_f<0x126>(hb), w6, a2);
        a3 = __builtin_fmaf(ror_f<0x127>(hb), w7, a3);
        a0 = __builtin_fmaf(ror_f<0x128>(hb), w8, a0);
        a1 = __builtin_fmaf(ror_f<0x129>(hb), w9, a1);
        a2 = __builtin_fmaf(ror_f<0x12A>(hb), w10, a2);
        a3 = __builtin_fmaf(ror_f<0x12B>(hb), w11, a3);
        a0 = __builtin_fmaf(ror_f<0x12C>(hb), w12, a0);
        a1 = __builtin_fmaf(ror_f<0x12D>(hb), w13, a1);
        a2 = __builtin_fmaf(ror_f<0x12E>(hb), w14, a2);
        a3 = __builtin_fmaf(ror_f<0x12F>(hb), w15, a3);
        float dot = (a0 + a1) + (a2 + a3);
        // combine the two 16-term partials (lanes l and l^32 share output i)
        u2v cp = swap32(dot, dot);
        float other = __uint_as_float(selA32 ? cp[0] : cp[1]);
        float pre = dot + other + __builtin_fmaf(xv, wih, bias);
        h = tanh_fast(pre);
        // dense head: y = tanh(wd . h + bd), direction-agnostic rotate-add
        float p = h * wd;
        p += ror_f<0x128>(p);
        p += ror_f<0x124>(p);
        p += ror_f<0x122>(p);
        p += ror_f<0x121>(p);
        u2v qp = swap16(p, p);
        float q = __uint_as_float(selA16 ? qp[0] : qp[1]);
        return tanh_fast(p + q + bdv);
    };

    for (int g = 0; g < Tn / 4; ++g) {
        int gn = g + 2;
        if (gn > Tn / 4 - 1) gn = Tn / 4 - 1;
        f4 xC = *reinterpret_cast<const f4*>(xb + gn * 4);   // prefetch 2 groups ahead
        float y0 = step(xA.x);
        float y1 = step(xA.y);
        float y2 = step(xA.z);
        float y3 = step(xA.w);
        if (lid == 0) {
            f4 yv = {y0, y1, y2, y3};
            *reinterpret_cast<f4*>(yb + g * 4) = yv;
        }
        xA = xB;
        xB = xC;
    }
    if (lid < 32) h_out[b * Hn + lid] = h;
}

extern "C" void kernel_launch(void* const* d_in, const int* in_sizes, int n_in,
                              void* d_out, int out_size, void* d_ws, size_t ws_size,
                              hipStream_t stream) {
    (void)in_sizes; (void)n_in; (void)out_size; (void)d_ws; (void)ws_size;
    const float* x   = (const float*)d_in[0];
    const float* ph  = (const float*)d_in[1];
    const float* Wih = (const float*)d_in[2];
    const float* Whh = (const float*)d_in[3];
    const float* bih = (const float*)d_in[4];
    const float* bhh = (const float*)d_in[5];
    const float* Wd  = (const float*)d_in[6];
    const float* bd  = (const float*)d_in[7];
    float* yout = (float*)d_out;
    float* hout = yout + (size_t)Bn * Tn;
    rnn_fused_kernel<<<dim3(Bn), dim3(64), 0, stream>>>(
        x, ph, Wih, Whh, bih, bhh, Wd, bd, yout, hout);
}